// Round 8
// baseline (246.909 us; speedup 1.0000x reference)
//
#include <hip/hip_runtime.h>
#include <cstdint>

// Shapes: B=8, C=256, H=W=64 -> N=4096, d=32, groups=32 (8 ch/group)

typedef __bf16 bf16x8 __attribute__((ext_vector_type(8)));
typedef float f32x4 __attribute__((ext_vector_type(4)));
typedef float f32x16 __attribute__((ext_vector_type(16)));
typedef unsigned int u32x4 __attribute__((ext_vector_type(4)));
typedef unsigned short u16x4 __attribute__((ext_vector_type(4)));
typedef unsigned short u16x8 __attribute__((ext_vector_type(8)));

#define DEVI __device__ __forceinline__

DEVI unsigned short f2bf(float f) {
    __bf16 h = (__bf16)f;               // RNE fptrunc
    return __builtin_bit_cast(unsigned short, h);
}
DEVI float bf2f(unsigned short u) {
    unsigned int x = ((unsigned int)u) << 16;
    return __builtin_bit_cast(float, x);
}

DEVI f32x4 mfma16(bf16x8 a, bf16x8 b, f32x4 c) {
    return __builtin_amdgcn_mfma_f32_16x16x32_bf16(a, b, c, 0, 0, 0);
}
DEVI f32x16 mfma32(bf16x8 a, bf16x8 b, f32x16 c) {
    return __builtin_amdgcn_mfma_f32_32x32x16_bf16(a, b, c, 0, 0, 0);
}

// async global->LDS, 16B per lane, wave-uniform LDS base + lane*16
DEVI void glds16(const unsigned short* g, unsigned short* l) {
    const __attribute__((address_space(1))) unsigned int* gp =
        reinterpret_cast<const __attribute__((address_space(1))) unsigned int*>(
            reinterpret_cast<uintptr_t>(g));
    __attribute__((address_space(3))) unsigned int* lp =
        reinterpret_cast<__attribute__((address_space(3))) unsigned int*>(
            reinterpret_cast<uintptr_t>(l));
    __builtin_amdgcn_global_load_lds(gp, lp, 16, 0, 0);
}

// raw barrier without the compiler's vmcnt(0)-drain; manual waits only
DEVI void barrier_raw() {
    asm volatile("" ::: "memory");
    __builtin_amdgcn_s_barrier();
    asm volatile("" ::: "memory");
}
DEVI void wait_vm0() {
    // SIMM16: vmcnt[3:0]=0, expcnt[6:4]=7, lgkmcnt[13:8]=0x3F, vmcnt[5:4]=0
    __builtin_amdgcn_s_waitcnt(0x3F70);
}

// log2(e)/sqrt(32): folded into Wq so S exits QK-MFMA in exp2 domain
#define QSCALE 0.2550663133f
#define MFIX   12.0f

// ---------------- group norm -> h^T (B*N, C) bf16 ----------------
// Single-read: reduction and normalize passes use the same cv[8] registers
// (32 VGPRs across the reduction; bitwise-identical per-thread sum order).
__global__ __launch_bounds__(1024) void k_gnorm(
        const float* __restrict__ x, const float* __restrict__ gw,
        const float* __restrict__ gb, unsigned short* __restrict__ ht) {
    int bg = blockIdx.x;               // 256 blocks = 8 batches * 32 groups
    int b = bg >> 5, g = bg & 31;
    const float* xb = x + ((size_t)(b * 256 + g * 8)) * 4096;  // 8 contiguous rows
    int t = threadIdx.x;
    int n0 = t * 4;
    f32x4 cv[8];
    #pragma unroll
    for (int c = 0; c < 8; c++) cv[c] = *(const f32x4*)(xb + c * 4096 + n0);
    float s1 = 0.f, s2 = 0.f;
    #pragma unroll
    for (int c = 0; c < 8; c++) {
        #pragma unroll
        for (int j = 0; j < 4; j++) { s1 += cv[c][j]; s2 += cv[c][j] * cv[c][j]; }
    }
    #pragma unroll
    for (int off = 1; off < 64; off <<= 1) {
        s1 += __shfl_xor(s1, off);
        s2 += __shfl_xor(s2, off);
    }
    __shared__ float red[34];
    int wv_ = t >> 6;
    if ((t & 63) == 0) { red[wv_ * 2] = s1; red[wv_ * 2 + 1] = s2; }
    __syncthreads();
    if (t == 0) {
        float a = 0.f, q = 0.f;
        #pragma unroll
        for (int i = 0; i < 16; i++) { a += red[i * 2]; q += red[i * 2 + 1]; }
        float mean = a * (1.f / 32768.f);
        float var = q * (1.f / 32768.f) - mean * mean;
        red[32] = mean; red[33] = rsqrtf(var + 1e-5f);
    }
    __syncthreads();
    float mean = red[32], rstd = red[33];
    float wv8[8], bv8[8];
    #pragma unroll
    for (int c = 0; c < 8; c++) { wv8[c] = gw[g * 8 + c] * rstd; bv8[c] = gb[g * 8 + c] - mean * rstd * gw[g * 8 + c]; }
    #pragma unroll
    for (int j = 0; j < 4; j++) {
        u16x8 pk;
        #pragma unroll
        for (int c = 0; c < 8; c++) pk[c] = f2bf(cv[c][j] * wv8[c] + bv8[c]);
        *(u16x8*)(&ht[((size_t)(b * 4096 + n0 + j)) * 256 + g * 8]) = pk;  // 16B store
    }
}

// ---------------- GEMM  C[M x Ncols] = A[M x 256] * W[Ncols x 256]^T ----------------
// Weights are read as fp32 and converted to bf16 DURING B-staging (replaces
// the old k_pack dispatch; bit-identical f2bf RNE sequence, weights are
// KB-scale and cache-resident so the wider reads are free).
// EPI 2: fp32 transposed + residual: out[b][o][n] = x + gamma*acc.  W = Wproj.
// EPI 3: merged QK+V projection — y==0: Wq(x QSCALE, rows 0..31)+Wk(rows
//        32..63) -> qk row-major (ldout=64); y>=1: Wv -> Vt[b][o][n] bf16
//        transposed with key-dim bit2<->bit3 swap (n0=(y-1)*64).
// Grid 2D (x: m-panels, y: n-blocks); 1D XCD swizzle measured SLOWER (round 1).
template <int EPI>
__global__ __launch_bounds__(256) void k_gemm(
        const unsigned short* __restrict__ A, void* __restrict__ outp,
        const float* __restrict__ xres, const float* __restrict__ gamma, int ldout,
        const float* __restrict__ wqf, const float* __restrict__ wkf,
        const float* __restrict__ wvf, void* __restrict__ outp2) {
    __shared__ unsigned short lA[128 * 72];
    __shared__ unsigned short lB[64 * 72];
    int t = threadIdx.x;
    int m0 = blockIdx.x * 128, n0 = blockIdx.y * 64;
    if (EPI == 3) {
        if (blockIdx.y == 0) n0 = 0;
        else n0 = (blockIdx.y - 1) * 64;
    }
    int w = t >> 6, lane = t & 63, l15 = lane & 15, quad = lane >> 4;
    f32x4 z4 = {0.f, 0.f, 0.f, 0.f};
    f32x4 acc[2][4];
    #pragma unroll
    for (int i = 0; i < 2; i++)
        #pragma unroll
        for (int j = 0; j < 4; j++) acc[i][j] = z4;

    // fp32 weight row fetch + convert: 8 bf16 for (tile row, global col gc)
    auto ldB8 = [&](int row, int gc) -> u16x8 {
        const float* src;
        float sc = 1.f;
        if (EPI == 3) {
            if (blockIdx.y == 0) {
                if (row < 32) { src = wqf + (size_t)row * 256 + gc; sc = QSCALE; }
                else          { src = wkf + (size_t)(row - 32) * 256 + gc; }
            } else {
                src = wvf + (size_t)(n0 + row) * 256 + gc;
            }
        } else {
            src = wvf + (size_t)(n0 + row) * 256 + gc;   // EPI2: wvf = Wproj
        }
        f32x4 a = *(const f32x4*)src;
        f32x4 b2 = *(const f32x4*)(src + 4);
        u16x8 r;
        #pragma unroll
        for (int j = 0; j < 4; j++) { r[j] = f2bf(a[j] * sc); r[4 + j] = f2bf(b2[j] * sc); }
        return r;
    };

    for (int kb = 0; kb < 4; kb++) {
        #pragma unroll
        for (int i = 0; i < 4; i++) {
            int ch = i * 256 + t;
            int row = ch >> 3, col = (ch & 7) * 8;
            u32x4 v = *(const u32x4*)(A + (size_t)(m0 + row) * 256 + kb * 64 + col);
            *(u32x4*)(&lA[row * 72 + col]) = v;
        }
        #pragma unroll
        for (int i = 0; i < 2; i++) {
            int ch = i * 256 + t;
            int row = ch >> 3, col = (ch & 7) * 8;
            u16x8 v = ldB8(row, kb * 64 + col);
            *(u16x8*)(&lB[row * 72 + col]) = v;
        }
        __syncthreads();
        #pragma unroll
        for (int ks = 0; ks < 2; ks++) {
            bf16x8 af[2], bfr[4];
            #pragma unroll
            for (int fr = 0; fr < 2; fr++)
                af[fr] = *(const bf16x8*)(&lA[(w * 32 + fr * 16 + l15) * 72 + ks * 32 + quad * 8]);
            #pragma unroll
            for (int fn = 0; fn < 4; fn++)
                bfr[fn] = *(const bf16x8*)(&lB[(fn * 16 + l15) * 72 + ks * 32 + quad * 8]);
            #pragma unroll
            for (int fr = 0; fr < 2; fr++)
                #pragma unroll
                for (int fn = 0; fn < 4; fn++)
                    acc[fr][fn] = mfma16(af[fr], bfr[fn], acc[fr][fn]);
        }
        __syncthreads();
    }

    bool epi0 = (EPI == 3 && blockIdx.y == 0);
    bool epi1 = (EPI == 3 && blockIdx.y != 0);
    if (epi0) {
        unsigned short* out = (unsigned short*)outp;
        #pragma unroll
        for (int fr = 0; fr < 2; fr++)
            #pragma unroll
            for (int fn = 0; fn < 4; fn++)
                #pragma unroll
                for (int r = 0; r < 4; r++) {
                    int m = m0 + w * 32 + fr * 16 + quad * 4 + r;
                    int n = n0 + fn * 16 + l15;
                    out[(size_t)m * ldout + n] = f2bf(acc[fr][fn][r]);
                }
    } else if (epi1) {
        unsigned short* out = (unsigned short*)outp2;
        int b = m0 >> 12, nb = (m0 & 4095) + w * 32;
        int swq = ((quad & 1) << 1) | (quad >> 1);   // bit2<->bit3 swap of n within 16
        #pragma unroll
        for (int fr = 0; fr < 2; fr++)
            #pragma unroll
            for (int fn = 0; fn < 4; fn++) {
                int o = n0 + fn * 16 + l15;
                int n = nb + fr * 16 + swq * 4;
                u16x4 pk;
                #pragma unroll
                for (int r = 0; r < 4; r++) pk[r] = f2bf(acc[fr][fn][r]);
                *(u16x4*)(&out[(((size_t)(b * 256 + o)) << 12) + n]) = pk;
            }
    } else {
        float* out = (float*)outp;
        float gm = gamma[0];
        int b = m0 >> 12, nb = (m0 & 4095) + w * 32;
        #pragma unroll
        for (int fr = 0; fr < 2; fr++)
            #pragma unroll
            for (int fn = 0; fn < 4; fn++) {
                int o = n0 + fn * 16 + l15;
                int n = nb + fr * 16 + quad * 4;
                size_t base = (((size_t)(b * 256 + o)) << 12) + n;
                f32x4 xv = *(const f32x4*)(xres + base);
                f32x4 ov;
                #pragma unroll
                for (int r = 0; r < 4; r++) ov[r] = xv[r] + gm * acc[fr][fn][r];
                *(f32x4*)(out + base) = ov;
            }
    }
}

// ---------------- flash attention: 32x32 MFMA, dbuf, o-split, LIGHT WAVES ----------------
// QK: (B*N, 64) bf16 (q cols 0..31 pre-scaled, k cols 32..63).
// Vt: (B, 256, N) bf16, key-dim sigma-permuted (bit2<->bit3 per 16-group).
// Grid 1024 = 8 b x 64 qblk(64q) x 2 oh(128 o-chans). 4 waves = 2 qh(32q) x 2 kh.
//
// Round-7 lesson: the binding constraint is a fixed per-key-tile latency floor
// (vmcnt(0) drain + barrier + LDS fill), not MFMA/VALU work — shrinking work
// left dur flat while stall grew to 41%. This round attacks the stall with
// TLP: halve the per-wave output tile (Oacc 128 -> 64 VGPRs, one q-tile per
// wave) so waves fit the 170-VGPR budget for THREE waves/SIMD
// (__launch_bounds__(256,3); m69 pool: 512 regs/SIMD). LDS stays 40KB ->
// 3 blocks/CU = 120KB. Chip-wide MFMA/exp/staging totals identical to the
// proven round-5 kernel — only wave granularity + residency change; the extra
// co-resident block fills each block's drain window.
// Spill/occupancy tripwire: VGPR > 170 -> falls back to 2 blocks/CU = round-5
// perf (same structure), WRITE_SIZE >> 17 MB -> spill, revert.
__global__ __launch_bounds__(256, 3) void k_flash(
        const unsigned short* __restrict__ QK, const unsigned short* __restrict__ Vt,
        unsigned short* __restrict__ Oa) {
    __shared__ __align__(16) char smem[40960];   // dbuf 2 x (4KB K + 16KB V); epilogue reuse
    int id = blockIdx.x;
    int b = id & 7;                    // batch <-> XCD affinity
    int r3 = id >> 3;
    int oh = r3 & 1, qblk = r3 >> 1;   // o-half, q-block(64)
    int t = threadIdx.x, w = t >> 6, ln = t & 63;
    int l31 = ln & 31, h = ln >> 5;
    int qh = w >> 1, kh = w & 1;

    // persistent Q B-frags for this wave's single 32-q tile
    const unsigned short* qrow = QK + ((size_t)(b * 4096 + qblk * 64 + qh * 32 + l31)) * 64;
    bf16x8 qb0 = *(const bf16x8*)(qrow + h * 8);
    bf16x8 qb1 = *(const bf16x8*)(qrow + 16 + h * 8);

    // staging: K tile (wave w stages keys w*16..+16), chunk-swizzled for A-frag reads
    int cgK = (ln & 3) ^ ((ln >> 2) & 3) ^ ((ln >> 4) & 3);
    const unsigned short* gK = QK + ((size_t)(b * 4096 + w * 16 + (ln >> 2))) * 64 + 32 + cgK * 8;
    // V half-tile: wave w stages o-rows oh*128 + w*32..+32, chunk-swizzled
    int vc8 = (ln & 7) ^ ((ln >> 3) & 7);
    const unsigned short* gV = Vt + (((size_t)(b * 256 + oh * 128 + w * 32 + (ln >> 3))) << 12) + vc8 * 8;

    // double buffers: K 4KB + V 16KB each
    unsigned short* lK0 = (unsigned short*)smem;
    unsigned short* lV0 = (unsigned short*)(smem + 4096);
    unsigned short* lK1 = (unsigned short*)(smem + 20480);
    unsigned short* lV1 = (unsigned short*)(smem + 24576);
    unsigned short* sK0 = lK0 + w * 512;
    unsigned short* sV0 = lV0 + w * 2048;
    unsigned short* sK1 = lK1 + w * 512;
    unsigned short* sV1 = lV1 + w * 2048;

    f32x16 z16;
    #pragma unroll
    for (int i = 0; i < 16; i++) z16[i] = 0.f;
    f32x16 minit;
    #pragma unroll
    for (int i = 0; i < 16; i++) minit[i] = -MFIX;
    f32x16 Oacc[4];
    #pragma unroll
    for (int i = 0; i < 4; i++) Oacc[i] = z16;
    float lsum = 0.f;                  // per-lane partial rowsum (q=l31, this (kh,h) keys)

    // loop-invariant LDS read offsets
    int gl = (l31 & 3) ^ ((l31 >> 2) & 3);
    const unsigned short* kf0p0 = lK0 + (kh * 32 + l31) * 32 + ((0 + h) ^ gl) * 8;
    const unsigned short* kf1p0 = lK0 + (kh * 32 + l31) * 32 + ((2 + h) ^ gl) * 8;
    const unsigned short* kf0p1 = lK1 + (kh * 32 + l31) * 32 + ((0 + h) ^ gl) * 8;
    const unsigned short* kf1p1 = lK1 + (kh * 32 + l31) * 32 + ((2 + h) ^ gl) * 8;
    int slotA = ((kh * 4 + 0 * 2 + h) ^ (ln & 7)) * 8;
    int slotB = ((kh * 4 + 1 * 2 + h) ^ (ln & 7)) * 8;

    auto stage = [&](int kn, unsigned short* sK, unsigned short* sV) {
        glds16(gK + (size_t)kn * 4096, sK);
        #pragma unroll
        for (int j = 0; j < 4; j++)
            glds16(gV + ((size_t)j * 8 << 12) + kn * 64, sV + j * 512);
    };

    auto compute = [&](const unsigned short* kf0p, const unsigned short* kf1p,
                       const unsigned short* lV) {
        bf16x8 kf0 = *(const bf16x8*)kf0p;
        bf16x8 kf1 = *(const bf16x8*)kf1p;
        f32x16 St = mfma32(kf0, qb0, minit);
        St = mfma32(kf1, qb1, St);
        u16x8 p0u, p1u;
        float s = 0.f;
        #pragma unroll
        for (int j = 0; j < 8; j++) {
            float e0 = __builtin_amdgcn_exp2f(St[j]);
            float e1 = __builtin_amdgcn_exp2f(St[8 + j]);
            s += e0 + e1;                       // rowsum in VALU (lane=q, regs=keys)
            p0u[j] = f2bf(e0);
            p1u[j] = f2bf(e1);
        }
        lsum += s;
        bf16x8 pa0 = __builtin_bit_cast(bf16x8, p0u);
        bf16x8 pa1 = __builtin_bit_cast(bf16x8, p1u);
        __builtin_amdgcn_s_setprio(1);
        #pragma unroll
        for (int nt = 0; nt < 4; nt++) {
            bf16x8 vf = *(const bf16x8*)(lV + (nt * 32 + l31) * 64 + slotA);
            Oacc[nt] = mfma32(pa0, vf, Oacc[nt]);
        }
        #pragma unroll
        for (int nt = 0; nt < 4; nt++) {
            bf16x8 vf = *(const bf16x8*)(lV + (nt * 32 + l31) * 64 + slotB);
            Oacc[nt] = mfma32(pa1, vf, Oacc[nt]);
        }
        __builtin_amdgcn_s_setprio(0);
    };

    stage(0, sK0, sV0);                 // preload tile 0 into buf0
    for (int kt = 0; kt < 64; kt += 2) {
        // --- even tile: compute buf0, prefetch kt+1 into buf1 ---
        wait_vm0();                     // drain buf0's loads (issued 1 iter ago)
        barrier_raw();
        stage(kt + 1, sK1, sV1);
        compute(kf0p0, kf1p0, lV0);
        // --- odd tile: compute buf1, prefetch kt+2 into buf0 ---
        wait_vm0();
        barrier_raw();
        if (kt + 2 < 64) stage(kt + 2, sK0, sV0);
        compute(kf0p1, kf1p1, lV1);
    }
    // finish rowsum: combine the two h-halves (lane l31 and l31+32 hold
    // complementary key subsets for the same q)
    lsum += __shfl_xor(lsum, 32);
    __syncthreads();                    // all LDS reads done before smem reuse

    // ---- epilogue via smem reuse ----
    // O partials bytes [0, 16384); lsum floats [8192, 8320) = bytes [32768, 33280)
    float* sf = (float*)smem;
    int lbase = (kh ? 8192 : 8256) + qh * 32 + l31;
    sf[lbase] = lsum;
    if (kh == 1) {                      // publish O partials (bf16)
        #pragma unroll
        for (int nt = 0; nt < 4; nt++)
            #pragma unroll
            for (int rg = 0; rg < 2; rg++) {
                u16x8 pk;
                #pragma unroll
                for (int j = 0; j < 8; j++) pk[j] = f2bf(Oacc[nt][rg * 8 + j]);
                *(u16x8*)(smem + qh * 8192 + nt * 2048 + rg * 1024 + ln * 16) = pk;
            }
    }
    __syncthreads();
    if (kh == 0) {                      // reduce + normalize + store
        float rl[16];
        #pragma unroll
        for (int r = 0; r < 16; r++) {
            int row = (r & 3) + 8 * (r >> 2) + 4 * h;
            float l = sf[8192 + qh * 32 + row] + sf[8256 + qh * 32 + row];
            rl[r] = 1.f / l;
        }
        size_t rb = (size_t)(b * 4096 + qblk * 64 + qh * 32);
        #pragma unroll
        for (int nt = 0; nt < 4; nt++)
            #pragma unroll
            for (int rg = 0; rg < 2; rg++) {
                u16x8 pk = *(const u16x8*)(smem + qh * 8192 + nt * 2048 + rg * 1024 + ln * 16);
                #pragma unroll
                for (int j = 0; j < 8; j++) {
                    int r = rg * 8 + j;
                    float val = (Oacc[nt][r] + bf2f(pk[j])) * rl[r];
                    int row = (r & 3) + 8 * (r >> 2) + 4 * h;
                    Oa[(rb + row) * 256 + oh * 128 + nt * 32 + l31] = f2bf(val);
                }
            }
    }
}

// ---------------- launch ----------------
extern "C" void kernel_launch(void* const* d_in, const int* in_sizes, int n_in,
                              void* d_out, int out_size, void* d_ws, size_t ws_size,
                              hipStream_t stream) {
    const float* x  = (const float*)d_in[0];
    const float* nw = (const float*)d_in[1];
    const float* nb = (const float*)d_in[2];
    const float* wq = (const float*)d_in[3];
    const float* wk = (const float*)d_in[4];
    const float* wv = (const float*)d_in[5];
    const float* wp = (const float*)d_in[6];
    const float* gm = (const float*)d_in[7];

    char* p = (char*)d_ws;
    unsigned short* ht  = (unsigned short*)p; p += (size_t)32768 * 256 * 2;  // 16 MB
    unsigned short* qk  = (unsigned short*)p; p += (size_t)32768 * 64 * 2;   // 4 MB
    unsigned short* vt  = (unsigned short*)p; p += (size_t)8 * 256 * 4096 * 2; // 16 MB
    unsigned short* oa  = (unsigned short*)p; p += (size_t)32768 * 256 * 2;  // 16 MB

    k_gnorm<<<dim3(256), dim3(1024), 0, stream>>>(x, nw, nb, ht);
    // merged QK-proj (y=0, Wq/Wk converted in-staging) + V-proj (y=1..4)
    k_gemm<3><<<dim3(256, 5), dim3(256), 0, stream>>>(ht, (void*)qk, nullptr, nullptr, 64, wq, wk, wv, (void*)vt);
    k_flash<<<dim3(1024), dim3(256), 0, stream>>>(qk, vt, oa);
    // output projection + residual (Wproj converted in-staging)
    k_gemm<2><<<dim3(256, 4), dim3(256), 0, stream>>>(oa, d_out, x, gm, 0, nullptr, nullptr, wp, nullptr);
}

// Round 9
// 223.522 us; speedup vs baseline: 1.1046x; 1.1046x over previous
//
#include <hip/hip_runtime.h>
#include <cstdint>

// Shapes: B=8, C=256, H=W=64 -> N=4096, d=32, groups=32 (8 ch/group)

typedef __bf16 bf16x8 __attribute__((ext_vector_type(8)));
typedef float f32x4 __attribute__((ext_vector_type(4)));
typedef float f32x16 __attribute__((ext_vector_type(16)));
typedef unsigned int u32x4 __attribute__((ext_vector_type(4)));
typedef unsigned short u16x4 __attribute__((ext_vector_type(4)));
typedef unsigned short u16x8 __attribute__((ext_vector_type(8)));

#define DEVI __device__ __forceinline__

DEVI unsigned short f2bf(float f) {
    __bf16 h = (__bf16)f;               // RNE fptrunc
    return __builtin_bit_cast(unsigned short, h);
}
DEVI float bf2f(unsigned short u) {
    unsigned int x = ((unsigned int)u) << 16;
    return __builtin_bit_cast(float, x);
}

DEVI f32x4 mfma16(bf16x8 a, bf16x8 b, f32x4 c) {
    return __builtin_amdgcn_mfma_f32_16x16x32_bf16(a, b, c, 0, 0, 0);
}
DEVI f32x16 mfma32(bf16x8 a, bf16x8 b, f32x16 c) {
    return __builtin_amdgcn_mfma_f32_32x32x16_bf16(a, b, c, 0, 0, 0);
}

// async global->LDS, 16B per lane, wave-uniform LDS base + lane*16
DEVI void glds16(const unsigned short* g, unsigned short* l) {
    const __attribute__((address_space(1))) unsigned int* gp =
        reinterpret_cast<const __attribute__((address_space(1))) unsigned int*>(
            reinterpret_cast<uintptr_t>(g));
    __attribute__((address_space(3))) unsigned int* lp =
        reinterpret_cast<__attribute__((address_space(3))) unsigned int*>(
            reinterpret_cast<uintptr_t>(l));
    __builtin_amdgcn_global_load_lds(gp, lp, 16, 0, 0);
}

// raw barrier without the compiler's vmcnt(0)-drain; manual waits only
DEVI void barrier_raw() {
    asm volatile("" ::: "memory");
    __builtin_amdgcn_s_barrier();
    asm volatile("" ::: "memory");
}
DEVI void wait_vm0() {
    // SIMM16: vmcnt[3:0]=0, expcnt[6:4]=7, lgkmcnt[13:8]=0x3F, vmcnt[5:4]=0
    __builtin_amdgcn_s_waitcnt(0x3F70);
}

// log2(e)/sqrt(32): folded into Wq so S exits QK-MFMA in exp2 domain
#define QSCALE 0.2550663133f
#define MFIX   12.0f

// ---------------- group norm -> h^T (B*N, C) bf16 ----------------
// Single-read: reduction and normalize passes use the same cv[8] registers
// (32 VGPRs across the reduction; bitwise-identical per-thread sum order).
__global__ __launch_bounds__(1024) void k_gnorm(
        const float* __restrict__ x, const float* __restrict__ gw,
        const float* __restrict__ gb, unsigned short* __restrict__ ht) {
    int bg = blockIdx.x;               // 256 blocks = 8 batches * 32 groups
    int b = bg >> 5, g = bg & 31;
    const float* xb = x + ((size_t)(b * 256 + g * 8)) * 4096;  // 8 contiguous rows
    int t = threadIdx.x;
    int n0 = t * 4;
    f32x4 cv[8];
    #pragma unroll
    for (int c = 0; c < 8; c++) cv[c] = *(const f32x4*)(xb + c * 4096 + n0);
    float s1 = 0.f, s2 = 0.f;
    #pragma unroll
    for (int c = 0; c < 8; c++) {
        #pragma unroll
        for (int j = 0; j < 4; j++) { s1 += cv[c][j]; s2 += cv[c][j] * cv[c][j]; }
    }
    #pragma unroll
    for (int off = 1; off < 64; off <<= 1) {
        s1 += __shfl_xor(s1, off);
        s2 += __shfl_xor(s2, off);
    }
    __shared__ float red[34];
    int wv_ = t >> 6;
    if ((t & 63) == 0) { red[wv_ * 2] = s1; red[wv_ * 2 + 1] = s2; }
    __syncthreads();
    if (t == 0) {
        float a = 0.f, q = 0.f;
        #pragma unroll
        for (int i = 0; i < 16; i++) { a += red[i * 2]; q += red[i * 2 + 1]; }
        float mean = a * (1.f / 32768.f);
        float var = q * (1.f / 32768.f) - mean * mean;
        red[32] = mean; red[33] = rsqrtf(var + 1e-5f);
    }
    __syncthreads();
    float mean = red[32], rstd = red[33];
    float wv8[8], bv8[8];
    #pragma unroll
    for (int c = 0; c < 8; c++) { wv8[c] = gw[g * 8 + c] * rstd; bv8[c] = gb[g * 8 + c] - mean * rstd * gw[g * 8 + c]; }
    #pragma unroll
    for (int j = 0; j < 4; j++) {
        u16x8 pk;
        #pragma unroll
        for (int c = 0; c < 8; c++) pk[c] = f2bf(cv[c][j] * wv8[c] + bv8[c]);
        *(u16x8*)(&ht[((size_t)(b * 4096 + n0 + j)) * 256 + g * 8]) = pk;  // 16B store
    }
}

// ---------------- GEMM  C[M x Ncols] = A[M x 256] * W[Ncols x 256]^T ----------------
// Weights are read as fp32 and converted to bf16 DURING B-staging (replaces
// the old k_pack dispatch; bit-identical f2bf RNE sequence, weights are
// KB-scale and cache-resident so the wider reads are free).
// EPI 2: fp32 transposed + residual: out[b][o][n] = x + gamma*acc.  W = Wproj.
// EPI 3: merged QK+V projection — y==0: Wq(x QSCALE, rows 0..31)+Wk(rows
//        32..63) -> qk row-major (ldout=64); y>=1: Wv -> Vt[b][o][n] bf16
//        transposed with key-dim bit2<->bit3 swap (n0=(y-1)*64).
// Grid 2D (x: m-panels, y: n-blocks); 1D XCD swizzle measured SLOWER (round 1).
template <int EPI>
__global__ __launch_bounds__(256) void k_gemm(
        const unsigned short* __restrict__ A, void* __restrict__ outp,
        const float* __restrict__ xres, const float* __restrict__ gamma, int ldout,
        const float* __restrict__ wqf, const float* __restrict__ wkf,
        const float* __restrict__ wvf, void* __restrict__ outp2) {
    __shared__ unsigned short lA[128 * 72];
    __shared__ unsigned short lB[64 * 72];
    int t = threadIdx.x;
    int m0 = blockIdx.x * 128, n0 = blockIdx.y * 64;
    if (EPI == 3) {
        if (blockIdx.y == 0) n0 = 0;
        else n0 = (blockIdx.y - 1) * 64;
    }
    int w = t >> 6, lane = t & 63, l15 = lane & 15, quad = lane >> 4;
    f32x4 z4 = {0.f, 0.f, 0.f, 0.f};
    f32x4 acc[2][4];
    #pragma unroll
    for (int i = 0; i < 2; i++)
        #pragma unroll
        for (int j = 0; j < 4; j++) acc[i][j] = z4;

    // fp32 weight row fetch + convert: 8 bf16 for (tile row, global col gc)
    auto ldB8 = [&](int row, int gc) -> u16x8 {
        const float* src;
        float sc = 1.f;
        if (EPI == 3) {
            if (blockIdx.y == 0) {
                if (row < 32) { src = wqf + (size_t)row * 256 + gc; sc = QSCALE; }
                else          { src = wkf + (size_t)(row - 32) * 256 + gc; }
            } else {
                src = wvf + (size_t)(n0 + row) * 256 + gc;
            }
        } else {
            src = wvf + (size_t)(n0 + row) * 256 + gc;   // EPI2: wvf = Wproj
        }
        f32x4 a = *(const f32x4*)src;
        f32x4 b2 = *(const f32x4*)(src + 4);
        u16x8 r;
        #pragma unroll
        for (int j = 0; j < 4; j++) { r[j] = f2bf(a[j] * sc); r[4 + j] = f2bf(b2[j] * sc); }
        return r;
    };

    for (int kb = 0; kb < 4; kb++) {
        #pragma unroll
        for (int i = 0; i < 4; i++) {
            int ch = i * 256 + t;
            int row = ch >> 3, col = (ch & 7) * 8;
            u32x4 v = *(const u32x4*)(A + (size_t)(m0 + row) * 256 + kb * 64 + col);
            *(u32x4*)(&lA[row * 72 + col]) = v;
        }
        #pragma unroll
        for (int i = 0; i < 2; i++) {
            int ch = i * 256 + t;
            int row = ch >> 3, col = (ch & 7) * 8;
            u16x8 v = ldB8(row, kb * 64 + col);
            *(u16x8*)(&lB[row * 72 + col]) = v;
        }
        __syncthreads();
        #pragma unroll
        for (int ks = 0; ks < 2; ks++) {
            bf16x8 af[2], bfr[4];
            #pragma unroll
            for (int fr = 0; fr < 2; fr++)
                af[fr] = *(const bf16x8*)(&lA[(w * 32 + fr * 16 + l15) * 72 + ks * 32 + quad * 8]);
            #pragma unroll
            for (int fn = 0; fn < 4; fn++)
                bfr[fn] = *(const bf16x8*)(&lB[(fn * 16 + l15) * 72 + ks * 32 + quad * 8]);
            #pragma unroll
            for (int fr = 0; fr < 2; fr++)
                #pragma unroll
                for (int fn = 0; fn < 4; fn++)
                    acc[fr][fn] = mfma16(af[fr], bfr[fn], acc[fr][fn]);
        }
        __syncthreads();
    }

    bool epi0 = (EPI == 3 && blockIdx.y == 0);
    bool epi1 = (EPI == 3 && blockIdx.y != 0);
    if (epi0) {
        unsigned short* out = (unsigned short*)outp;
        #pragma unroll
        for (int fr = 0; fr < 2; fr++)
            #pragma unroll
            for (int fn = 0; fn < 4; fn++)
                #pragma unroll
                for (int r = 0; r < 4; r++) {
                    int m = m0 + w * 32 + fr * 16 + quad * 4 + r;
                    int n = n0 + fn * 16 + l15;
                    out[(size_t)m * ldout + n] = f2bf(acc[fr][fn][r]);
                }
    } else if (epi1) {
        unsigned short* out = (unsigned short*)outp2;
        int b = m0 >> 12, nb = (m0 & 4095) + w * 32;
        int swq = ((quad & 1) << 1) | (quad >> 1);   // bit2<->bit3 swap of n within 16
        #pragma unroll
        for (int fr = 0; fr < 2; fr++)
            #pragma unroll
            for (int fn = 0; fn < 4; fn++) {
                int o = n0 + fn * 16 + l15;
                int n = nb + fr * 16 + swq * 4;
                u16x4 pk;
                #pragma unroll
                for (int r = 0; r < 4; r++) pk[r] = f2bf(acc[fr][fn][r]);
                *(u16x4*)(&out[(((size_t)(b * 256 + o)) << 12) + n]) = pk;
            }
    } else {
        float* out = (float*)outp;
        float gm = gamma[0];
        int b = m0 >> 12, nb = (m0 & 4095) + w * 32;
        #pragma unroll
        for (int fr = 0; fr < 2; fr++)
            #pragma unroll
            for (int fn = 0; fn < 4; fn++) {
                int o = n0 + fn * 16 + l15;
                int n = nb + fr * 16 + quad * 4;
                size_t base = (((size_t)(b * 256 + o)) << 12) + n;
                f32x4 xv = *(const f32x4*)(xres + base);
                f32x4 ov;
                #pragma unroll
                for (int r = 0; r < 4; r++) ov[r] = xv[r] + gm * acc[fr][fn][r];
                *(f32x4*)(out + base) = ov;
            }
    }
}

// ---------------- flash attention: 32x32 MFMA, dbuf, o-split, 512-thread blocks ----------------
// QK: (B*N, 64) bf16 (q cols 0..31 pre-scaled, k cols 32..63).
// Vt: (B, 256, N) bf16, key-dim sigma-permuted (bit2<->bit3 per 16-group).
// Grid 256 = 8 b x 16 qblk(256q) x 2 oh(128 o-chans) -> exactly 1 block/CU.
// 8 waves = 4 qh(64q) x 2 kh. Each wave is IDENTICAL to the proven round-5
// wave (2 qt2-tiles x 128o x kh-half, Oacc[2][4]=128 VGPR, the register-
// optimal compute ordering — 3 spill incidents say do not touch).
//
// Round-7/8 consolidated model: flash time ~ (block-tiles per CU) x (fixed
// tile cost: stage instr + vmcnt drain + barrier). Halving per-block q
// DOUBLED staging (r7: 2x V bytes; r8: 2x blocks) and regressed. This round
// goes the OTHER way: 256q per block amortizes V staging over 2x the output.
// Per-CU: 64 block-tiles (was 128), staging 1.28MB (was 2.56MB); residency
// unchanged (8 waves/CU = 2/SIMD). Chip staging 0.65GB -> 0.33GB.
// Tripwires: WRITE >> 17MB = spill; bank-conflict should HALVE to ~2.1M.
__global__ __launch_bounds__(512, 2) void k_flash(
        const unsigned short* __restrict__ QK, const unsigned short* __restrict__ Vt,
        unsigned short* __restrict__ Oa) {
    // buffers: K0@0(4KB) V0@4096(16KB) K1@20480(4KB) V1@24576(16KB) = 40KB
    // epilogue reuse: O-partials bytes [0,65536), lsum floats [16384,16896)
    __shared__ __align__(16) char smem[67584];
    int id = blockIdx.x;
    int b = id & 7;                    // batch <-> XCD affinity
    int r3 = id >> 3;
    int oh = r3 & 1, qblk = r3 >> 1;   // o-half, q-block(256)
    int t = threadIdx.x, w = t >> 6, ln = t & 63;
    int l31 = ln & 31, h = ln >> 5;
    int qh = w >> 1, kh = w & 1;       // qh 0..3, kh 0..1
    int q0 = qblk * 256 + qh * 64;     // this wave's 64-q range (2 tiles of 32)

    // persistent Q B-frags: B[k=d][n=q]; lane: q=l31, d = s*16 + h*8 + j
    bf16x8 qb0[2], qb1[2];
    #pragma unroll
    for (int qt2 = 0; qt2 < 2; qt2++) {
        const unsigned short* qrow = QK + ((size_t)(b * 4096 + q0 + qt2 * 32 + l31)) * 64;
        qb0[qt2] = *(const bf16x8*)(qrow + h * 8);
        qb1[qt2] = *(const bf16x8*)(qrow + 16 + h * 8);
    }

    // staging: K tile by waves 0..3 (wave w stages keys w*16..+16), chunk-swizzled
    int cgK = (ln & 3) ^ ((ln >> 2) & 3) ^ ((ln >> 4) & 3);
    const unsigned short* gK = QK + ((size_t)(b * 4096 + (w & 3) * 16 + (ln >> 2))) * 64 + 32 + cgK * 8;
    // V half-tile: wave w stages o-rows oh*128 + w*16..+16 (2 glds16), chunk-swizzled
    int vc8 = (ln & 7) ^ ((ln >> 3) & 7);
    const unsigned short* gV = Vt + (((size_t)(b * 256 + oh * 128 + w * 16 + (ln >> 3))) << 12) + vc8 * 8;

    // double buffers: K 4KB + V 16KB each
    unsigned short* lK0 = (unsigned short*)smem;
    unsigned short* lV0 = (unsigned short*)(smem + 4096);
    unsigned short* lK1 = (unsigned short*)(smem + 20480);
    unsigned short* lV1 = (unsigned short*)(smem + 24576);
    unsigned short* sK0 = lK0 + (w & 3) * 512;
    unsigned short* sV0 = lV0 + w * 1024;
    unsigned short* sK1 = lK1 + (w & 3) * 512;
    unsigned short* sV1 = lV1 + w * 1024;

    f32x16 z16;
    #pragma unroll
    for (int i = 0; i < 16; i++) z16[i] = 0.f;
    f32x16 minit;
    #pragma unroll
    for (int i = 0; i < 16; i++) minit[i] = -MFIX;
    f32x16 Oacc[2][4];
    #pragma unroll
    for (int qt2 = 0; qt2 < 2; qt2++)
        #pragma unroll
        for (int i = 0; i < 4; i++) Oacc[qt2][i] = z16;
    float lsum[2] = {0.f, 0.f};        // per-lane partial rowsum (q=l31, this (kh,h) keys)

    // loop-invariant LDS read offsets
    int gl = (l31 & 3) ^ ((l31 >> 2) & 3);
    const unsigned short* kf0p0 = lK0 + (kh * 32 + l31) * 32 + ((0 + h) ^ gl) * 8;
    const unsigned short* kf1p0 = lK0 + (kh * 32 + l31) * 32 + ((2 + h) ^ gl) * 8;
    const unsigned short* kf0p1 = lK1 + (kh * 32 + l31) * 32 + ((0 + h) ^ gl) * 8;
    const unsigned short* kf1p1 = lK1 + (kh * 32 + l31) * 32 + ((2 + h) ^ gl) * 8;
    int slotA = ((kh * 4 + 0 * 2 + h) ^ (ln & 7)) * 8;
    int slotB = ((kh * 4 + 1 * 2 + h) ^ (ln & 7)) * 8;

    auto stage = [&](int kn, unsigned short* sK, unsigned short* sV) {
        if (w < 4) glds16(gK + (size_t)kn * 4096, sK);
        #pragma unroll
        for (int j = 0; j < 2; j++)
            glds16(gV + ((size_t)j * 8 << 12) + kn * 64, sV + j * 512);
    };

    auto compute = [&](const unsigned short* kf0p, const unsigned short* kf1p,
                       const unsigned short* lV) {
        bf16x8 kf0 = *(const bf16x8*)kf0p;
        bf16x8 kf1 = *(const bf16x8*)kf1p;
        bf16x8 pa[2][2];
        #pragma unroll
        for (int qt2 = 0; qt2 < 2; qt2++) {
            f32x16 St = mfma32(kf0, qb0[qt2], minit);
            St = mfma32(kf1, qb1[qt2], St);
            u16x8 p0u, p1u;
            float s = 0.f;
            #pragma unroll
            for (int j = 0; j < 8; j++) {
                float e0 = __builtin_amdgcn_exp2f(St[j]);
                float e1 = __builtin_amdgcn_exp2f(St[8 + j]);
                s += e0 + e1;                       // rowsum in VALU (lane=q, regs=keys)
                p0u[j] = f2bf(e0);
                p1u[j] = f2bf(e1);
            }
            lsum[qt2] += s;
            pa[qt2][0] = __builtin_bit_cast(bf16x8, p0u);
            pa[qt2][1] = __builtin_bit_cast(bf16x8, p1u);
        }
        __builtin_amdgcn_s_setprio(1);
        #pragma unroll
        for (int nt = 0; nt < 4; nt++) {
            bf16x8 vf = *(const bf16x8*)(lV + (nt * 32 + l31) * 64 + slotA);
            Oacc[0][nt] = mfma32(pa[0][0], vf, Oacc[0][nt]);
            Oacc[1][nt] = mfma32(pa[1][0], vf, Oacc[1][nt]);
        }
        #pragma unroll
        for (int nt = 0; nt < 4; nt++) {
            bf16x8 vf = *(const bf16x8*)(lV + (nt * 32 + l31) * 64 + slotB);
            Oacc[0][nt] = mfma32(pa[0][1], vf, Oacc[0][nt]);
            Oacc[1][nt] = mfma32(pa[1][1], vf, Oacc[1][nt]);
        }
        __builtin_amdgcn_s_setprio(0);
    };

    stage(0, sK0, sV0);                 // preload tile 0 into buf0
    for (int kt = 0; kt < 64; kt += 2) {
        // --- even tile: compute buf0, prefetch kt+1 into buf1 ---
        wait_vm0();                     // drain buf0's loads (issued 1 iter ago)
        barrier_raw();
        stage(kt + 1, sK1, sV1);
        compute(kf0p0, kf1p0, lV0);
        // --- odd tile: compute buf1, prefetch kt+2 into buf0 ---
        wait_vm0();
        barrier_raw();
        if (kt + 2 < 64) stage(kt + 2, sK0, sV0);
        compute(kf0p1, kf1p1, lV1);
    }
    // finish rowsums: combine the two h-halves (lane l31 and l31+32 hold
    // complementary key subsets for the same q)
    #pragma unroll
    for (int qt2 = 0; qt2 < 2; qt2++) lsum[qt2] += __shfl_xor(lsum[qt2], 32);
    __syncthreads();                    // all LDS reads done before smem reuse

    // ---- epilogue via smem reuse ----
    float* sf = (float*)smem;
    // lsum publish: floats [16384 + kh-region(256) ...], region = 4qh x 2qt2 x 32
    int lbase = (kh ? 16384 : 16640) + qh * 64 + l31;
    sf[lbase] = lsum[0];
    sf[lbase + 32] = lsum[1];
    if (kh == 1) {                      // publish O partials (bf16), 64KB
        #pragma unroll
        for (int qt2 = 0; qt2 < 2; qt2++)
            #pragma unroll
            for (int nt = 0; nt < 4; nt++)
                #pragma unroll
                for (int rg = 0; rg < 2; rg++) {
                    u16x8 pk;
                    #pragma unroll
                    for (int j = 0; j < 8; j++) pk[j] = f2bf(Oacc[qt2][nt][rg * 8 + j]);
                    *(u16x8*)(smem + qh * 16384 + qt2 * 8192 + nt * 2048 + rg * 1024 + ln * 16) = pk;
                }
    }
    __syncthreads();
    if (kh == 0) {                      // reduce + normalize + store
        #pragma unroll
        for (int qt2 = 0; qt2 < 2; qt2++) {
            float rl[16];
            #pragma unroll
            for (int r = 0; r < 16; r++) {
                int row = (r & 3) + 8 * (r >> 2) + 4 * h;
                float l = sf[16384 + qh * 64 + qt2 * 32 + row] +
                          sf[16640 + qh * 64 + qt2 * 32 + row];
                rl[r] = 1.f / l;
            }
            size_t rb = (size_t)(b * 4096 + qblk * 256 + qh * 64 + qt2 * 32);
            #pragma unroll
            for (int nt = 0; nt < 4; nt++)
                #pragma unroll
                for (int rg = 0; rg < 2; rg++) {
                    u16x8 pk = *(const u16x8*)(smem + qh * 16384 + qt2 * 8192 + nt * 2048 + rg * 1024 + ln * 16);
                    #pragma unroll
                    for (int j = 0; j < 8; j++) {
                        int r = rg * 8 + j;
                        float val = (Oacc[qt2][nt][r] + bf2f(pk[j])) * rl[r];
                        int row = (r & 3) + 8 * (r >> 2) + 4 * h;
                        Oa[(rb + row) * 256 + oh * 128 + nt * 32 + l31] = f2bf(val);
                    }
                }
        }
    }
}

// ---------------- launch ----------------
extern "C" void kernel_launch(void* const* d_in, const int* in_sizes, int n_in,
                              void* d_out, int out_size, void* d_ws, size_t ws_size,
                              hipStream_t stream) {
    const float* x  = (const float*)d_in[0];
    const float* nw = (const float*)d_in[1];
    const float* nb = (const float*)d_in[2];
    const float* wq = (const float*)d_in[3];
    const float* wk = (const float*)d_in[4];
    const float* wv = (const float*)d_in[5];
    const float* wp = (const float*)d_in[6];
    const float* gm = (const float*)d_in[7];

    char* p = (char*)d_ws;
    unsigned short* ht  = (unsigned short*)p; p += (size_t)32768 * 256 * 2;  // 16 MB
    unsigned short* qk  = (unsigned short*)p; p += (size_t)32768 * 64 * 2;   // 4 MB
    unsigned short* vt  = (unsigned short*)p; p += (size_t)8 * 256 * 4096 * 2; // 16 MB
    unsigned short* oa  = (unsigned short*)p; p += (size_t)32768 * 256 * 2;  // 16 MB

    k_gnorm<<<dim3(256), dim3(1024), 0, stream>>>(x, nw, nb, ht);
    // merged QK-proj (y=0, Wq/Wk converted in-staging) + V-proj (y=1..4)
    k_gemm<3><<<dim3(256, 5), dim3(256), 0, stream>>>(ht, (void*)qk, nullptr, nullptr, 64, wq, wk, wv, (void*)vt);
    k_flash<<<dim3(256), dim3(512), 0, stream>>>(qk, vt, oa);
    // output projection + residual (Wproj converted in-staging)
    k_gemm<2><<<dim3(256, 4), dim3(256), 0, stream>>>(oa, d_out, x, gm, 0, nullptr, nullptr, wp, nullptr);
}